// Round 1
// baseline (1585.646 us; speedup 1.0000x reference)
//
#include <hip/hip_runtime.h>

#define S_TOK 8192
#define DIM   1024
#define DIM2  2048
#define OUTN  1024

typedef __bf16 bf16x8 __attribute__((ext_vector_type(8)));
typedef float  f32x4  __attribute__((ext_vector_type(4)));
typedef short  s16x8  __attribute__((ext_vector_type(8)));
typedef unsigned short u16x4 __attribute__((ext_vector_type(4)));

__device__ __forceinline__ unsigned short f2bf(float x) {
  unsigned u = __builtin_bit_cast(unsigned, x);
  u = (u + 0x7FFFu + ((u >> 16) & 1u)) >> 16;
  return (unsigned short)u;
}

// Swizzled LDS byte offset for a [128][64] bf16 tile (idx-major, k inner).
// XOR of bits 4-6 with (idx ^ idx>>3): keeps 16B alignment for b128 accesses,
// spreads both fragment reads (idx varies by 1 across lanes) and scatter
// staging writes (idx varies by 8 across lanes) to <=2-way bank conflicts.
__device__ __forceinline__ int lds_off(int idx, int k) {
  int b = (idx << 7) + (k << 1);
  b ^= ((idx ^ (idx >> 3)) & 7) << 4;
  return b;
}

__global__ __launch_bounds__(256) void cvt_f32_bf16(const float* __restrict__ in,
                                                    unsigned short* __restrict__ out, int n4) {
  int i = blockIdx.x * 256 + threadIdx.x;
  if (i >= n4) return;
  float4 v = ((const float4*)in)[i];
  u16x4 o;
  o[0] = f2bf(v.x); o[1] = f2bf(v.y); o[2] = f2bf(v.z); o[3] = f2bf(v.w);
  *(u16x4*)(out + (size_t)i * 4) = o;
}

// In-place row softmax over DIM2=2048 bf16 columns. One block (256 thr) per row.
__global__ __launch_bounds__(256) void softmax_rows(unsigned short* __restrict__ T) {
  const int tid = threadIdx.x;
  unsigned short* p = T + (size_t)blockIdx.x * DIM2 + tid * 8;
  s16x8 v = *(const s16x8*)p;
  float f[8];
#pragma unroll
  for (int j = 0; j < 8; ++j)
    f[j] = __builtin_bit_cast(float, (unsigned)((unsigned short)v[j]) << 16);
  float m = f[0];
#pragma unroll
  for (int j = 1; j < 8; ++j) m = fmaxf(m, f[j]);
#pragma unroll
  for (int off = 32; off; off >>= 1) m = fmaxf(m, __shfl_xor(m, off, 64));
  __shared__ float redm[4], reds[4];
  if ((tid & 63) == 0) redm[tid >> 6] = m;
  __syncthreads();
  m = fmaxf(fmaxf(redm[0], redm[1]), fmaxf(redm[2], redm[3]));
  float s = 0.f;
#pragma unroll
  for (int j = 0; j < 8; ++j) { f[j] = __expf(f[j] - m); s += f[j]; }
#pragma unroll
  for (int off = 32; off; off >>= 1) s += __shfl_xor(s, off, 64);
  if ((tid & 63) == 0) reds[tid >> 6] = s;
  __syncthreads();
  s = reds[0] + reds[1] + reds[2] + reds[3];
  float inv = 1.0f / s;
  s16x8 o;
#pragma unroll
  for (int j = 0; j < 8; ++j) o[j] = (short)f2bf(f[j] * inv);
  *(s16x8*)p = o;
}

// Tiled bf16 MFMA GEMM: C[M,N] = epi(op(A) @ op(B) * scale + bias).
// A_MODE 0: A stored [M,K] row-major (lda = K-stride). For k >= ksplit reads A2
//           at (k - ksplit)  -> virtual concat along K.
// A_MODE 1: A stored [K,M] row-major (lda = M-stride)  -> computes A^T @ B.
// B_MODE 0: B stored [K,N] row-major (ldb = N-stride).
// B_MODE 1: B stored [N,K] row-major (ldb = K-stride)  -> computes A @ B^T.
// Tile 128x128, BK=64, 4 waves (each 64x64 = 4x4 MFMA 16x16x32 tiles).
template <int A_MODE, int B_MODE, int OUT_BF16>
__global__ __launch_bounds__(256, 2) void gemm_k(
    const unsigned short* __restrict__ A, const unsigned short* __restrict__ A2,
    int ksplit, int lda,
    const unsigned short* __restrict__ B, int ldb,
    const float* __restrict__ bias, void* __restrict__ Cv, int ldc,
    int M, int N, int K, float scale, int do_relu) {
  __shared__ char lds[32768];
  char* As = lds;
  char* Bs = lds + 16384;
  const int tid  = threadIdx.x;
  const int lane = tid & 63;
  const int wave = tid >> 6;
  const int wm = (wave >> 1) << 6;
  const int wn = (wave & 1) << 6;
  const int m0 = blockIdx.y << 7;
  const int n0 = blockIdx.x << 7;

  f32x4 acc[4][4];
#pragma unroll
  for (int i = 0; i < 4; ++i)
#pragma unroll
    for (int j = 0; j < 4; ++j) acc[i][j] = {0.f, 0.f, 0.f, 0.f};

  for (int k0 = 0; k0 < K; k0 += 64) {
    // ---- stage A tile into As[m][k] ----
    if (A_MODE == 0) {
#pragma unroll
      for (int i = 0; i < 4; ++i) {
        int c = tid + (i << 8);          // 1024 chunks of 16B
        int row = c >> 3, kc = c & 7;
        int gk = k0 + (kc << 3);
        const unsigned short* src = (gk < ksplit)
            ? (A  + (size_t)(m0 + row) * lda + gk)
            : (A2 + (size_t)(m0 + row) * lda + (gk - ksplit));
        s16x8 v = *(const s16x8*)src;
        *(s16x8*)(As + lds_off(row, kc << 3)) = v;
      }
    } else {  // A stored [K,M]: coalesced global read, u16 scatter into LDS
#pragma unroll
      for (int i = 0; i < 4; ++i) {
        int c = tid + (i << 8);
        int kr = c >> 4, mc = c & 15;
        s16x8 v = *(const s16x8*)(A + (size_t)(k0 + kr) * lda + (m0 + (mc << 3)));
#pragma unroll
        for (int j = 0; j < 8; ++j)
          *(unsigned short*)(As + lds_off((mc << 3) + j, kr)) = (unsigned short)v[j];
      }
    }
    // ---- stage B tile into Bs[n][k] ----
    if (B_MODE == 0) {  // B stored [K,N]: scatter
#pragma unroll
      for (int i = 0; i < 4; ++i) {
        int c = tid + (i << 8);
        int kr = c >> 4, nc = c & 15;
        s16x8 v = *(const s16x8*)(B + (size_t)(k0 + kr) * ldb + (n0 + (nc << 3)));
#pragma unroll
        for (int j = 0; j < 8; ++j)
          *(unsigned short*)(Bs + lds_off((nc << 3) + j, kr)) = (unsigned short)v[j];
      }
    } else {  // B stored [N,K]: contiguous
#pragma unroll
      for (int i = 0; i < 4; ++i) {
        int c = tid + (i << 8);
        int row = c >> 3, kc = c & 7;
        s16x8 v = *(const s16x8*)(B + (size_t)(n0 + row) * ldb + k0 + (kc << 3));
        *(s16x8*)(Bs + lds_off(row, kc << 3)) = v;
      }
    }
    __syncthreads();
#pragma unroll
    for (int ks = 0; ks < 2; ++ks) {
      bf16x8 af[4], bfr[4];
      int kk = (ks << 5) + ((lane >> 4) << 3);
#pragma unroll
      for (int t = 0; t < 4; ++t) {
        af[t]  = *(const bf16x8*)(As + lds_off(wm + (t << 4) + (lane & 15), kk));
        bfr[t] = *(const bf16x8*)(Bs + lds_off(wn + (t << 4) + (lane & 15), kk));
      }
#pragma unroll
      for (int mt = 0; mt < 4; ++mt)
#pragma unroll
        for (int nt = 0; nt < 4; ++nt)
          acc[mt][nt] = __builtin_amdgcn_mfma_f32_16x16x32_bf16(af[mt], bfr[nt], acc[mt][nt], 0, 0, 0);
    }
    __syncthreads();
  }

  // ---- epilogue: C/D layout col = lane&15, row = (lane>>4)*4 + r ----
#pragma unroll
  for (int nt = 0; nt < 4; ++nt) {
    int col = n0 + wn + (nt << 4) + (lane & 15);
    float bv = bias ? bias[col] : 0.0f;
#pragma unroll
    for (int mt = 0; mt < 4; ++mt) {
      f32x4 a = acc[mt][nt];
#pragma unroll
      for (int r = 0; r < 4; ++r) {
        int rowg = m0 + wm + (mt << 4) + ((lane >> 4) << 2) + r;
        float v = a[r] * scale + bv;
        if (do_relu) v = fmaxf(v, 0.0f);
        if (OUT_BF16) ((unsigned short*)Cv)[(size_t)rowg * ldc + col] = f2bf(v);
        else          ((float*)Cv)[(size_t)rowg * ldc + col] = v;
      }
    }
  }
}

extern "C" void kernel_launch(void* const* d_in, const int* in_sizes, int n_in,
                              void* d_out, int out_size, void* d_ws, size_t ws_size,
                              hipStream_t stream) {
  const float* X   = (const float*)d_in[0];
  const float* Y   = (const float*)d_in[1];
  const float* R   = (const float*)d_in[2];
  const float* Wi  = (const float*)d_in[3];
  const float* bi  = (const float*)d_in[4];
  const float* Wo  = (const float*)d_in[5];
  const float* bo  = (const float*)d_in[6];
  const float* Wc  = (const float*)d_in[7];
  const float* bc  = (const float*)d_in[8];
  const float* Wf  = (const float*)d_in[9];
  const float* bf_ = (const float*)d_in[10];
  float* out = (float*)d_out;

  char* ws = (char*)d_ws;
  size_t off = 0;
  auto alloc = [&](size_t b) { char* p = ws + off; off += (b + 255) & ~(size_t)255; return p; };
  unsigned short* Xb   = (unsigned short*)alloc((size_t)S_TOK * DIM  * 2);
  unsigned short* Yb   = (unsigned short*)alloc((size_t)S_TOK * DIM  * 2);
  unsigned short* Rb   = (unsigned short*)alloc((size_t)S_TOK * DIM  * 2);
  unsigned short* Wib  = (unsigned short*)alloc((size_t)DIM  * DIM2 * 2);
  unsigned short* Wob  = (unsigned short*)alloc((size_t)DIM  * DIM2 * 2);
  unsigned short* Wcb  = (unsigned short*)alloc((size_t)DIM2 * DIM2 * 2);
  unsigned short* Wfb  = (unsigned short*)alloc((size_t)DIM2 * OUTN * 2);
  unsigned short* iq   = (unsigned short*)alloc((size_t)S_TOK * DIM2 * 2);
  unsigned short* oq   = (unsigned short*)alloc((size_t)S_TOK * DIM2 * 2);
  unsigned short* icm  = (unsigned short*)alloc((size_t)S_TOK * DIM2 * 2);
  unsigned short* iqk  = (unsigned short*)alloc((size_t)DIM2 * DIM2 * 2);
  unsigned short* oqk  = (unsigned short*)alloc((size_t)DIM2 * DIM2 * 2);
  unsigned short* meta = (unsigned short*)alloc((size_t)DIM2 * DIM2 * 2);
  unsigned short* res  = (unsigned short*)alloc((size_t)S_TOK * DIM2 * 2);

  auto cvt = [&](const float* s, unsigned short* d, int n) {
    int n4 = n >> 2;
    cvt_f32_bf16<<<dim3((n4 + 255) / 256), dim3(256), 0, stream>>>(s, d, n4);
  };
  cvt(X, Xb, S_TOK * DIM);
  cvt(Y, Yb, S_TOK * DIM);
  cvt(R, Rb, S_TOK * DIM);
  cvt(Wi, Wib, DIM * DIM2);
  cvt(Wo, Wob, DIM * DIM2);
  cvt(Wc, Wcb, DIM2 * DIM2);
  cvt(Wf, Wfb, DIM2 * OUTN);

  const float rscale = 0.022097086912079608f;  // 1/sqrt(2048)

  // iq = softmax(X @ W_in + b_in) -- shared by both marches (x = input both times)
  gemm_k<0,0,1><<<dim3(DIM2/128, S_TOK/128), 256, 0, stream>>>(
      Xb, Xb, DIM, DIM, Wib, DIM2, bi, iq, DIM2, S_TOK, DIM2, DIM, 1.f, 0);
  softmax_rows<<<S_TOK, 256, 0, stream>>>(iq);

  for (int pass = 0; pass < 2; ++pass) {
    const unsigned short* Yp = (pass == 0) ? Yb : Rb;
    float* outp = out + (size_t)pass * S_TOK * OUTN;

    // oq = softmax(y @ W_out + b_out)
    gemm_k<0,0,1><<<dim3(DIM2/128, S_TOK/128), 256, 0, stream>>>(
        Yp, Yp, DIM, DIM, Wob, DIM2, bo, oq, DIM2, S_TOK, DIM2, DIM, 1.f, 0);
    softmax_rows<<<S_TOK, 256, 0, stream>>>(oq);

    // icm = softmax(concat(x,y) @ W_cat + b_cat)  (K-split concat: A for k<1024, A2 after)
    gemm_k<0,0,1><<<dim3(DIM2/128, S_TOK/128), 256, 0, stream>>>(
        Xb, Yp, DIM, DIM, Wcb, DIM2, bc, icm, DIM2, S_TOK, DIM2, DIM2, 1.f, 0);
    softmax_rows<<<S_TOK, 256, 0, stream>>>(icm);

    // iqk = iq^T @ icm ; oqk = oq^T @ icm   [2048,2048], K=8192
    gemm_k<1,0,1><<<dim3(DIM2/128, DIM2/128), 256, 0, stream>>>(
        iq, iq, S_TOK, DIM2, icm, DIM2, nullptr, iqk, DIM2, DIM2, DIM2, S_TOK, 1.f, 0);
    gemm_k<1,0,1><<<dim3(DIM2/128, DIM2/128), 256, 0, stream>>>(
        oq, oq, S_TOK, DIM2, icm, DIM2, nullptr, oqk, DIM2, DIM2, DIM2, S_TOK, 1.f, 0);

    // meta = relu(iqk @ oqk^T)   [2048,2048], K=2048
    gemm_k<0,1,1><<<dim3(DIM2/128, DIM2/128), 256, 0, stream>>>(
        iqk, iqk, DIM2, DIM2, oqk, DIM2, nullptr, meta, DIM2, DIM2, DIM2, DIM2, 1.f, 1);

    // res = (icm @ meta) / sqrt(2048)   [8192,2048], K=2048
    gemm_k<0,0,1><<<dim3(DIM2/128, S_TOK/128), 256, 0, stream>>>(
        icm, icm, DIM2, DIM2, meta, DIM2, nullptr, res, DIM2, S_TOK, DIM2, DIM2, rscale, 0);

    // out = relu(res @ W_fin + b_fin)   [8192,1024], K=2048, f32 output
    gemm_k<0,0,0><<<dim3(OUTN/128, S_TOK/128), 256, 0, stream>>>(
        res, res, DIM2, DIM2, Wfb, OUTN, bf_, outp, OUTN, S_TOK, OUTN, DIM2, 1.f, 1);
  }
  (void)in_sizes; (void)n_in; (void)out_size; (void)ws_size;
}